// Round 9
// baseline (334.787 us; speedup 1.0000x reference)
//
#include <hip/hip_runtime.h>
#include <hip/hip_bf16.h>
#include <math.h>

namespace {
constexpr int kN = 262144;
constexpr int kD = 64;
constexpr int kK = 512;
constexpr int kThreads = 512;           // 8 waves/block
constexpr int kRowsPerThread = 2;
constexpr int kRowsPerBlock = kThreads * kRowsPerThread;   // 1024
constexpr long long kLossOff = (long long)kN * kD;         // 16777216
constexpr long long kIdxOff  = kLossOff + 1;
constexpr float kLossScale = 1.25f / (float)((long long)kN * kD);
}

// d_out is poisoned 0xAA before every timed launch; the loss accumulator
// must start at zero. A plain kernel is unambiguously graph-capture-safe.
__global__ void vq_zero(float* __restrict__ out) {
    out[kLossOff] = 0.0f;
}

// 256 blocks x 512 threads, 1 block/CU (LDS-capped), 2 rows per thread.
// Codebook in LDS (128 KB); main-loop e-reads are wave-uniform broadcasts
// (conflict-free). R=2 halves LDS issue demand vs R=1: one broadcast
// ds_read_b128 per 16 issue-cycles per wave.
__global__ __launch_bounds__(kThreads, 2) void vq_main(
    const float* __restrict__ z,
    const float* __restrict__ cb,
    float* __restrict__ out)
{
    alignas(16) __shared__ float lds_cb[kK * kD];        // 128 KB
    alignas(16) __shared__ float lds_ee[kK];             // 2 KB
    __shared__ int   lds_idx[kRowsPerBlock];             // 4 KB
    __shared__ float lds_loss[kThreads / 64];

    const int tid = threadIdx.x;
    const long long base = (long long)blockIdx.x * kRowsPerBlock;

    // ---- 1. stage codebook to LDS, coalesced float4 ----
    {
        const float4* __restrict__ src = (const float4*)cb;
        float4* dst = (float4*)lds_cb;
        #pragma unroll
        for (int i = 0; i < (kK * kD / 4) / kThreads; ++i)   // 16 iters
            dst[i * kThreads + tid] = src[i * kThreads + tid];
    }

    // ---- 2. ||e_k||^2 from GLOBAL cb (L2-hot; avoids the 64-way LDS bank
    // conflict of row-strided LDS reads). Square then sequential ascending
    // sum, contraction off (match reference rounding). Fully unrolled so
    // all 64 loads are in flight (the s-chain order is unchanged). ----
    {
        #pragma clang fp contract(off)
        float s = 0.0f;
        const float* e = cb + tid * kD;
        #pragma unroll
        for (int d = 0; d < kD; ++d) { float p = e[d] * e[d]; s = s + p; }
        lds_ee[tid] = s;
    }

    // ---- 3. two z rows into registers (rows base+tid, base+512+tid) ----
    float4 zr4[kRowsPerThread][kD / 4];
    #pragma unroll
    for (int r = 0; r < kRowsPerThread; ++r) {
        const float4* __restrict__ zs =
            (const float4*)(z + (base + r * kThreads + tid) * kD);
        #pragma unroll
        for (int i = 0; i < kD / 4; ++i) zr4[r][i] = zs[i];
    }

    // ---- 4. ||z||^2 per row (square, sequential ascending sum) ----
    float zz[kRowsPerThread];
    #pragma unroll
    for (int r = 0; r < kRowsPerThread; ++r) {
        #pragma clang fp contract(off)
        float s = 0.0f;
        #pragma unroll
        for (int i = 0; i < kD / 4; ++i) {
            float p;
            p = zr4[r][i].x * zr4[r][i].x; s = s + p;
            p = zr4[r][i].y * zr4[r][i].y; s = s + p;
            p = zr4[r][i].z * zr4[r][i].z; s = s + p;
            p = zr4[r][i].w * zr4[r][i].w; s = s + p;
        }
        zz[r] = s;
    }

    __syncthreads();   // lds_cb + lds_ee ready

    // ---- 5. argmin over 512 codes: 4 codes x 2 rows in flight ----
    float dmin0 = __builtin_inff(), dmin1 = __builtin_inff();
    int best0 = 0, best1 = 0;

    for (int k0 = 0; k0 < kK; k0 += 4) {
        const float4* __restrict__ e0 = (const float4*)&lds_cb[(k0 + 0) * kD];
        const float4* __restrict__ e1 = (const float4*)&lds_cb[(k0 + 1) * kD];
        const float4* __restrict__ e2 = (const float4*)&lds_cb[(k0 + 2) * kD];
        const float4* __restrict__ e3 = (const float4*)&lds_cb[(k0 + 3) * kD];
        // a[row][code]; each chain accumulates d ascending with one
        // accumulator (matches sequential-K accumulation order).
        float a00 = 0.f, a01 = 0.f, a02 = 0.f, a03 = 0.f;
        float a10 = 0.f, a11 = 0.f, a12 = 0.f, a13 = 0.f;
        #pragma unroll
        for (int j = 0; j < kD / 4; ++j) {
            const float4 v0 = e0[j];
            const float4 v1 = e1[j];
            const float4 v2 = e2[j];
            const float4 v3 = e3[j];
            const float4 x0 = zr4[0][j];
            const float4 x1 = zr4[1][j];
            // 8 independent chains, round-robin: dep distance 16 issue-cyc.
            a00 = fmaf(x0.x, v0.x, a00); a01 = fmaf(x0.x, v1.x, a01);
            a02 = fmaf(x0.x, v2.x, a02); a03 = fmaf(x0.x, v3.x, a03);
            a10 = fmaf(x1.x, v0.x, a10); a11 = fmaf(x1.x, v1.x, a11);
            a12 = fmaf(x1.x, v2.x, a12); a13 = fmaf(x1.x, v3.x, a13);
            a00 = fmaf(x0.y, v0.y, a00); a01 = fmaf(x0.y, v1.y, a01);
            a02 = fmaf(x0.y, v2.y, a02); a03 = fmaf(x0.y, v3.y, a03);
            a10 = fmaf(x1.y, v0.y, a10); a11 = fmaf(x1.y, v1.y, a11);
            a12 = fmaf(x1.y, v2.y, a12); a13 = fmaf(x1.y, v3.y, a13);
            a00 = fmaf(x0.z, v0.z, a00); a01 = fmaf(x0.z, v1.z, a01);
            a02 = fmaf(x0.z, v2.z, a02); a03 = fmaf(x0.z, v3.z, a03);
            a10 = fmaf(x1.z, v0.z, a10); a11 = fmaf(x1.z, v1.z, a11);
            a12 = fmaf(x1.z, v2.z, a12); a13 = fmaf(x1.z, v3.z, a13);
            a00 = fmaf(x0.w, v0.w, a00); a01 = fmaf(x0.w, v1.w, a01);
            a02 = fmaf(x0.w, v2.w, a02); a03 = fmaf(x0.w, v3.w, a03);
            a10 = fmaf(x1.w, v0.w, a10); a11 = fmaf(x1.w, v1.w, a11);
            a12 = fmaf(x1.w, v2.w, a12); a13 = fmaf(x1.w, v3.w, a13);
        }
        // Reference rounding: mul, sub, add as separate fp32 ops.
        {
            #pragma clang fp contract(off)
            const float4 ee = *(const float4*)&lds_ee[k0];
            const float d00 = (zz[0] - 2.0f * a00) + ee.x;
            const float d01 = (zz[0] - 2.0f * a01) + ee.y;
            const float d02 = (zz[0] - 2.0f * a02) + ee.z;
            const float d03 = (zz[0] - 2.0f * a03) + ee.w;
            const float d10 = (zz[1] - 2.0f * a10) + ee.x;
            const float d11 = (zz[1] - 2.0f * a11) + ee.y;
            const float d12 = (zz[1] - 2.0f * a12) + ee.z;
            const float d13 = (zz[1] - 2.0f * a13) + ee.w;
            // strict < ascending k -> first-min tie-break (jnp.argmin)
            if (d00 < dmin0) { dmin0 = d00; best0 = k0 + 0; }
            if (d01 < dmin0) { dmin0 = d01; best0 = k0 + 1; }
            if (d02 < dmin0) { dmin0 = d02; best0 = k0 + 2; }
            if (d03 < dmin0) { dmin0 = d03; best0 = k0 + 3; }
            if (d10 < dmin1) { dmin1 = d10; best1 = k0 + 0; }
            if (d11 < dmin1) { dmin1 = d11; best1 = k0 + 1; }
            if (d12 < dmin1) { dmin1 = d12; best1 = k0 + 2; }
            if (d13 < dmin1) { dmin1 = d13; best1 = k0 + 3; }
        }
    }

    lds_idx[tid] = best0;
    lds_idx[kThreads + tid] = best1;

    // ---- 6. loss: dmin == ||z - q||^2 per row; total = 1.25 * mean ----
    float lsum = dmin0 + dmin1;
    #pragma unroll
    for (int off = 32; off > 0; off >>= 1)
        lsum += __shfl_down(lsum, off, 64);
    if ((tid & 63) == 0) lds_loss[tid >> 6] = lsum;

    // ---- 7. idx output (float; exact for values < 2^24) ----
    out[kIdxOff + base + tid] = (float)best0;
    out[kIdxOff + base + kThreads + tid] = (float)best1;

    __syncthreads();   // lds_idx + lds_loss ready

    if (tid == 0) {
        float t = 0.0f;
        #pragma unroll
        for (int w = 0; w < kThreads / 64; ++w) t += lds_loss[w];
        atomicAdd(&out[kLossOff], t * kLossScale);
    }

    // ---- 8. cooperative coalesced q_st store: each wave stores 128 rows,
    // 4 rows/iter (16 lanes x float4 = one row). q rows are read from
    // GLOBAL cb (L2-resident, 128 KB): avoids the 8-way LDS bank conflict
    // of the row-gather (every LDS row starts at bank 0 — stride 64 floats
    // = 2 bank wraps). Aggregate L2 read = 64 MB chip-wide ≈ 2 µs. ----
    const int wave = tid >> 6;
    const int lane = tid & 63;
    const int rgrp = lane >> 4;          // 0..3
    const int col4 = (lane & 15) * 4;    // element start within row
    #pragma unroll
    for (int t = 0; t < 32; ++t) {
        const int rl = wave * 128 + t * 4 + rgrp;
        const int ridx = lds_idx[rl];
        const float4 q4 = *(const float4*)&cb[ridx * kD + col4];
        *(float4*)&out[(base + rl) * kD + col4] = q4;
    }
}

extern "C" void kernel_launch(void* const* d_in, const int* in_sizes, int n_in,
                              void* d_out, int out_size, void* d_ws, size_t ws_size,
                              hipStream_t stream)
{
    const float* z  = (const float*)d_in[0];
    const float* cb = (const float*)d_in[1];
    float* out = (float*)d_out;

    vq_zero<<<1, 1, 0, stream>>>(out);
    vq_main<<<kN / kRowsPerBlock, kThreads, 0, stream>>>(z, cb, out);
}